// Round 9
// baseline (404.163 us; speedup 1.0000x reference)
//
#include <hip/hip_runtime.h>

typedef __bf16 bf16_t;
typedef __bf16 bf16x4 __attribute__((ext_vector_type(4)));
typedef __bf16 bf16x8 __attribute__((ext_vector_type(8)));
typedef float floatx4 __attribute__((ext_vector_type(4)));

#define B_    128
#define H_    14
#define HW_   196
#define C_    768
#define NH_   12
#define HD_   64
#define M_    25088
#define NQKV_ 2304
#define KDIM_ 768
#define BK_   64    // GEMM K-tile
#define NKT_  12    // KDIM_/BK_
#define VPAD_ 208   // v^T global row length (16B-aligned)
#define RSTR  72    // rT staging stride (bf16)
#define QSTR  104   // q'/k' augmented row stride in bf16
#define PSTR  232   // pb LDS row stride in bf16

// ---------------------------------------------------------------- async 16B global->LDS
__device__ __forceinline__ void async_cp16(const void* g, void* l) {
    __builtin_amdgcn_global_load_lds((const __attribute__((address_space(1))) void*)g,
                                     (__attribute__((address_space(3))) void*)l, 16, 0, 0);
}

// ---------------------------------------------------------------- cast x -> bf16
__global__ __launch_bounds__(256) void cast_x_kernel(const float* __restrict__ in,
                                                     bf16_t* __restrict__ out) {
    size_t i = ((size_t)blockIdx.x * 256 + threadIdx.x) * 8;
    float4 a = *(const float4*)(in + i);
    float4 b = *(const float4*)(in + i + 4);
    bf16x8 v;
    v[0] = (bf16_t)a.x; v[1] = (bf16_t)a.y; v[2] = (bf16_t)a.z; v[3] = (bf16_t)a.w;
    v[4] = (bf16_t)b.x; v[5] = (bf16_t)b.y; v[6] = (bf16_t)b.z; v[7] = (bf16_t)b.w;
    *(bf16x8*)(out + i) = v;
}

// ---------------------------------------------------------------- zero v^T padding cols [196,208)
__global__ __launch_bounds__(256) void zero_vpad_kernel(bf16_t* __restrict__ vtb) {
    int row = blockIdx.x * 256 + threadIdx.x;   // B_*NH_*HD_ = 98304 rows
    if (row < B_ * NH_ * HD_) {
        bf16_t* p = vtb + (size_t)row * VPAD_ + HW_;
        #pragma unroll
        for (int i = 0; i < 12; i++) p[i] = (bf16_t)0.f;
    }
}

// ------------------------------------------- transpose + cast weight (rows x cols) -> (cols x rows)
__global__ __launch_bounds__(256) void transpose_cast_kernel(const float* __restrict__ in,
                                                             bf16_t* __restrict__ out,
                                                             int rows, int cols) {
    __shared__ float tile[32][33];
    int c0 = blockIdx.x * 32, r0 = blockIdx.y * 32;
    for (int i = threadIdx.y; i < 32; i += 8) {
        int r = r0 + i, c = c0 + threadIdx.x;
        if (r < rows && c < cols) tile[i][threadIdx.x] = in[(size_t)r * cols + c];
    }
    __syncthreads();
    for (int i = threadIdx.y; i < 32; i += 8) {
        int orow = c0 + i;            // output row = input col
        int oc   = r0 + threadIdx.x;  // output col = input row
        if (orow < cols && oc < rows)
            out[(size_t)orow * rows + oc] = (bf16_t)tile[threadIdx.x][i];
    }
}

// ---------------------------------------------------------------- staging: one 128x64 tile slice (256 thr)
__device__ __forceinline__ void stage128(const bf16_t* __restrict__ G, int g0, int kt,
                                         bf16_t (*Lb)[BK_], int tid) {
    const int sr = tid >> 3, cc = tid & 7;
    #pragma unroll
    for (int i = 0; i < 4; i++) {
        int row  = sr + i * 32;                 // in-tile row 0..127
        int scol = ((cc ^ (row & 7)) * 8);      // swizzled source k-chunk
        async_cp16(G + (size_t)(g0 + row) * KDIM_ + kt * BK_ + scol, &Lb[row][cc * 8]);
    }
}

// ---------------------------------------------------------------- staging: one 256x64 tile (512 thr)
__device__ __forceinline__ void stage256(const bf16_t* __restrict__ G, int g0, int kt,
                                         bf16_t (*Lb)[BK_], int tid) {
    #pragma unroll
    for (int r = 0; r < 4; r++) {
        int idx = r * 512 + tid;                // 0..2047
        int row = idx >> 3, cc = idx & 7;
        int scol = (cc ^ (row & 7)) * 8;        // source-side XOR swizzle
        async_cp16(G + (size_t)(g0 + row) * KDIM_ + kt * BK_ + scol, &Lb[row][cc * 8]);
    }
}

// ---------------------------------------------------------------- 128-tile GEMM core, double-buffered.
__device__ __forceinline__ void gemm128_pipe(const bf16_t* __restrict__ A,
                                             const bf16_t* __restrict__ Bt,
                                             int m0, int n0,
                                             floatx4 acc[4][4],
                                             bf16_t (*As)[BK_], bf16_t (*Bs)[BK_]) {
    const int tid  = threadIdx.x;
    const int lane = tid & 63, wave = tid >> 6;
    const int wm = (wave & 1) << 6, wn = (wave >> 1) << 6;
    const int lrow = lane & 15, quad = lane >> 4;

    #pragma unroll
    for (int i = 0; i < 4; i++)
        #pragma unroll
        for (int j = 0; j < 4; j++) acc[i][j] = (floatx4){0.f, 0.f, 0.f, 0.f};

    stage128(A,  m0, 0, As, tid);
    stage128(Bt, n0, 0, Bs, tid);

    for (int kt = 0; kt < NKT_; kt++) {
        __builtin_amdgcn_sched_barrier(0);
        asm volatile("s_waitcnt vmcnt(0) lgkmcnt(0)" ::: "memory");
        __builtin_amdgcn_s_barrier();
        __builtin_amdgcn_sched_barrier(0);

        bf16_t (*Ab)[BK_] = As + (kt & 1) * 128;
        bf16_t (*Bb)[BK_] = Bs + (kt & 1) * 128;

        if (kt + 1 < NKT_) {
            stage128(A,  m0, kt + 1, As + ((kt + 1) & 1) * 128, tid);
            stage128(Bt, n0, kt + 1, Bs + ((kt + 1) & 1) * 128, tid);
        }

        #pragma unroll
        for (int kh = 0; kh < 2; kh++) {
            bf16x8 af[4], bfr[4];
            #pragma unroll
            for (int i = 0; i < 4; i++) {
                int rw = wm + i * 16 + lrow;
                af[i] = *(const bf16x8*)&Ab[rw][((kh * 4 + quad) ^ (rw & 7)) * 8];
            }
            #pragma unroll
            for (int j = 0; j < 4; j++) {
                int rw = wn + j * 16 + lrow;
                bfr[j] = *(const bf16x8*)&Bb[rw][((kh * 4 + quad) ^ (rw & 7)) * 8];
            }
            #pragma unroll
            for (int i = 0; i < 4; i++)
                #pragma unroll
                for (int j = 0; j < 4; j++)
                    acc[i][j] = __builtin_amdgcn_mfma_f32_16x16x32_bf16(af[i], bfr[j], acc[i][j], 0, 0, 0);
        }
    }
    __syncthreads();
}

// ---------------------------------------------------------------- QKV GEMM: 256x256 tile, 8 waves,
// double-buffered LDS (128 KB), 4 phases/K-tile, XCD-bijective block swizzle, TRUE counted vmcnt:
// tile kt+2 staged at phase 3 of tile kt; vmcnt(8) there certifies tile kt+1 (issued a full tile
// earlier) while kt+2's 8 loads stay in flight. Never drains to 0 mid-loop. q pre-scaled by 0.125.
__global__ __launch_bounds__(512, 2) void qkv_gemm_kernel(const bf16_t* __restrict__ A,
                                                          const bf16_t* __restrict__ Bt,
                                                          const float* __restrict__ bias,
                                                          bf16_t* __restrict__ qb,
                                                          bf16_t* __restrict__ kb,
                                                          bf16_t* __restrict__ vtb) {
    __shared__ __align__(16) char smem[131072];            // Ab[2][256][64] | Bb[2][256][64]
    bf16_t (*AbAll)[256][64] = (bf16_t(*)[256][64])smem;
    bf16_t (*BbAll)[256][64] = (bf16_t(*)[256][64])(smem + 65536);
    bf16_t (*Cs)[136]        = (bf16_t(*)[136])smem;       // epilogue union: 256x128 half (69,632 B)

    const int tid  = threadIdx.x;
    const int lane = tid & 63, wave = tid >> 6;
    const int wr = wave >> 2, wc = wave & 3;               // 2M x 4N wave grid
    const int lrow = lane & 15, quad = lane >> 4;
    const int c0 = ((quad ^ (lrow & 7)) * 8);              // kh=0 swizzled chunk
    const int c1 = (((4 + quad) ^ (lrow & 7)) * 8);        // kh=1

    // XCD-bijective swizzle (m204): nwg=882 -> q=110, r=2. Each XCD owns a contiguous
    // wgid chunk; within a chunk bn varies fastest -> A-panel reused within ONE XCD L2.
    const int nwg = 98 * 9;
    const int qq = nwg >> 3, rr8 = nwg & 7;
    const int xcd = blockIdx.x & 7, lid = blockIdx.x >> 3;
    const int wgid = (xcd < rr8 ? xcd * (qq + 1) : rr8 * (qq + 1) + (xcd - rr8) * qq) + lid;
    const int bm = wgid / 9, bn = wgid % 9;
    const int m0 = bm * 256, n0 = bn * 256;

    floatx4 acc[8][4];
    #pragma unroll
    for (int i = 0; i < 8; i++)
        #pragma unroll
        for (int j = 0; j < 4; j++) acc[i][j] = (floatx4){0.f, 0.f, 0.f, 0.f};

    // prologue: stage tiles 0 AND 1; certify tile 0, keep tile 1's 8 loads in flight
    stage256(A,  m0, 0, AbAll[0], tid);
    stage256(Bt, n0, 0, BbAll[0], tid);
    stage256(A,  m0, 1, AbAll[1], tid);
    stage256(Bt, n0, 1, BbAll[1], tid);
    asm volatile("s_waitcnt vmcnt(8)" ::: "memory");
    __builtin_amdgcn_s_barrier();
    __builtin_amdgcn_sched_barrier(0);

    for (int kt = 0; kt < NKT_; kt++) {
        bf16_t (*Ab)[64] = AbAll[kt & 1];
        bf16_t (*Bb)[64] = BbAll[kt & 1];
        const int arow = wr * 128 + lrow;
        const int brow = wc * 64 + lrow;

        bf16x8 af[4][2], bfA[2][2], bfB[2][2];

        // ---- phase 0: ds_read af(m-half 0) + bfA(n-q 0)
        #pragma unroll
        for (int i = 0; i < 4; i++) {
            af[i][0] = *(const bf16x8*)&Ab[arow + i * 16][c0];
            af[i][1] = *(const bf16x8*)&Ab[arow + i * 16][c1];
        }
        #pragma unroll
        for (int j = 0; j < 2; j++) {
            bfA[j][0] = *(const bf16x8*)&Bb[brow + j * 16][c0];
            bfA[j][1] = *(const bf16x8*)&Bb[brow + j * 16][c1];
        }
        __builtin_amdgcn_s_barrier();
        asm volatile("s_waitcnt lgkmcnt(0)" ::: "memory");
        __builtin_amdgcn_sched_barrier(0);
        __builtin_amdgcn_s_setprio(1);
        #pragma unroll
        for (int i = 0; i < 4; i++)
            #pragma unroll
            for (int j = 0; j < 2; j++) {
                acc[i][j] = __builtin_amdgcn_mfma_f32_16x16x32_bf16(af[i][0], bfA[j][0], acc[i][j], 0, 0, 0);
                acc[i][j] = __builtin_amdgcn_mfma_f32_16x16x32_bf16(af[i][1], bfA[j][1], acc[i][j], 0, 0, 0);
            }
        __builtin_amdgcn_s_setprio(0);
        __builtin_amdgcn_sched_barrier(0);
        __builtin_amdgcn_s_barrier();

        // ---- phase 1: ds_read bfB(n-q 1)
        #pragma unroll
        for (int j = 0; j < 2; j++) {
            bfB[j][0] = *(const bf16x8*)&Bb[brow + 32 + j * 16][c0];
            bfB[j][1] = *(const bf16x8*)&Bb[brow + 32 + j * 16][c1];
        }
        __builtin_amdgcn_s_barrier();
        asm volatile("s_waitcnt lgkmcnt(0)" ::: "memory");
        __builtin_amdgcn_sched_barrier(0);
        __builtin_amdgcn_s_setprio(1);
        #pragma unroll
        for (int i = 0; i < 4; i++)
            #pragma unroll
            for (int j = 0; j < 2; j++) {
                acc[i][2 + j] = __builtin_amdgcn_mfma_f32_16x16x32_bf16(af[i][0], bfB[j][0], acc[i][2 + j], 0, 0, 0);
                acc[i][2 + j] = __builtin_amdgcn_mfma_f32_16x16x32_bf16(af[i][1], bfB[j][1], acc[i][2 + j], 0, 0, 0);
            }
        __builtin_amdgcn_s_setprio(0);
        __builtin_amdgcn_sched_barrier(0);
        __builtin_amdgcn_s_barrier();

        // ---- phase 2: ds_read af(m-half 1)
        #pragma unroll
        for (int i = 0; i < 4; i++) {
            af[i][0] = *(const bf16x8*)&Ab[arow + 64 + i * 16][c0];
            af[i][1] = *(const bf16x8*)&Ab[arow + 64 + i * 16][c1];
        }
        __builtin_amdgcn_s_barrier();
        asm volatile("s_waitcnt lgkmcnt(0)" ::: "memory");
        __builtin_amdgcn_sched_barrier(0);
        __builtin_amdgcn_s_setprio(1);
        #pragma unroll
        for (int i = 0; i < 4; i++)
            #pragma unroll
            for (int j = 0; j < 2; j++) {
                acc[4 + i][j] = __builtin_amdgcn_mfma_f32_16x16x32_bf16(af[i][0], bfA[j][0], acc[4 + i][j], 0, 0, 0);
                acc[4 + i][j] = __builtin_amdgcn_mfma_f32_16x16x32_bf16(af[i][1], bfA[j][1], acc[4 + i][j], 0, 0, 0);
            }
        __builtin_amdgcn_s_setprio(0);
        __builtin_amdgcn_sched_barrier(0);
        __builtin_amdgcn_s_barrier();

        // ---- phase 3: stage tile kt+2 into buf kt&1 (vacated: ph0-2 reads retired by ph2
        // lgkm+barrier); MFMA; counted vmcnt(8) certifies tile kt+1 (issued at kt-1 ph3,
        // 4 phases old) while kt+2's 8 loads remain in flight.
        if (kt + 2 < NKT_) {
            stage256(A,  m0, kt + 2, AbAll[kt & 1], tid);
            stage256(Bt, n0, kt + 2, BbAll[kt & 1], tid);
        }
        __builtin_amdgcn_s_setprio(1);
        #pragma unroll
        for (int i = 0; i < 4; i++)
            #pragma unroll
            for (int j = 0; j < 2; j++) {
                acc[4 + i][2 + j] = __builtin_amdgcn_mfma_f32_16x16x32_bf16(af[i][0], bfB[j][0], acc[4 + i][2 + j], 0, 0, 0);
                acc[4 + i][2 + j] = __builtin_amdgcn_mfma_f32_16x16x32_bf16(af[i][1], bfB[j][1], acc[4 + i][2 + j], 0, 0, 0);
            }
        __builtin_amdgcn_s_setprio(0);
        __builtin_amdgcn_sched_barrier(0);
        if (kt + 2 < NKT_) {
            asm volatile("s_waitcnt vmcnt(8)" ::: "memory");
        } else {
            asm volatile("s_waitcnt vmcnt(0)" ::: "memory");
        }
        __builtin_amdgcn_s_barrier();
        __builtin_amdgcn_sched_barrier(0);
    }

    // ---------------- epilogue
    const int sel = n0 / C_;                    // 0=q 1=k 2=v (256-tiles never straddle)

    if (sel == 2) {
        #pragma unroll
        for (int j = 0; j < 4; j++) {
            int n = n0 + wc * 64 + j * 16 + lrow;
            float bv = bias[n];
            int nc = n - 2 * C_;
            int nh = nc >> 6, hd = nc & 63;
            #pragma unroll
            for (int i = 0; i < 8; i++) {
                int m = m0 + wr * 128 + i * 16 + quad * 4;
                int b = m / HW_, t = m - b * HW_;
                int head = b * NH_ + nh;
                ushort4 pk;
                bf16_t h;
                h = (bf16_t)(acc[i][j][0] + bv); pk.x = __builtin_bit_cast(unsigned short, h);
                h = (bf16_t)(acc[i][j][1] + bv); pk.y = __builtin_bit_cast(unsigned short, h);
                h = (bf16_t)(acc[i][j][2] + bv); pk.z = __builtin_bit_cast(unsigned short, h);
                h = (bf16_t)(acc[i][j][3] + bv); pk.w = __builtin_bit_cast(unsigned short, h);
                *(ushort4*)(vtb + ((size_t)head * HD_ + hd) * VPAD_ + t) = pk;
            }
        }
    } else {
        const float sc = (sel == 0) ? 0.125f : 1.0f;
        bf16_t* dst = sel ? kb : qb;
        const int n0s = n0 - sel * C_;
        // two half-passes through Cs[256][136]
        #pragma unroll
        for (int hh = 0; hh < 2; hh++) {
            __syncthreads();                     // K-loop LDS / previous half copy done
            if ((wc >> 1) == hh) {
                #pragma unroll
                for (int j = 0; j < 4; j++) {
                    int n = n0 + wc * 64 + j * 16 + lrow;
                    float bv = bias[n];
                    int ccol = (wc & 1) * 64 + j * 16 + lrow;   // col within half: 0..127
                    #pragma unroll
                    for (int i = 0; i < 8; i++)
                        #pragma unroll
                        for (int rr = 0; rr < 4; rr++)
                            Cs[wr * 128 + i * 16 + quad * 4 + rr][ccol] =
                                (bf16_t)((acc[i][j][rr] + bv) * sc);
                }
            }
            __syncthreads();
            // copy 256 x 128 half: 4096 uint4, 8 per thread
            #pragma unroll
            for (int u = 0; u < 8; u++) {
                int idx = tid + u * 512;
                int rr = idx >> 4, c = idx & 15;
                int m = m0 + rr;
                int b = m / HW_, t = m - b * HW_;
                int ncol = n0s + hh * 128 + c * 8;
                int nh = ncol >> 6, hd = ncol & 63;
                *(uint4*)(dst + (((size_t)(b * NH_ + nh)) * HW_ + t) * HD_ + hd) =
                    *(const uint4*)&Cs[rr][c * 8];
            }
        }
    }
}

// ---------------------------------------------------------------- proj GEMM + bias -> fp32 out
__global__ __launch_bounds__(256) void proj_gemm_kernel(const bf16_t* __restrict__ A,
                                                        const bf16_t* __restrict__ Bt,
                                                        const float* __restrict__ bias,
                                                        float* __restrict__ out) {
    __shared__ __align__(16) bf16_t As[256][BK_];   // double-buffered
    __shared__ __align__(16) bf16_t Bs[256][BK_];
    const int lin = blockIdx.x;
    const int g = lin / 24, r = lin - g * 24;
    const int m0 = (g * 4 + (r & 3)) * 128;
    const int n0 = (r >> 2) * 128;
    floatx4 acc[4][4];
    gemm128_pipe(A, Bt, m0, n0, acc, As, Bs);

    const int lane = threadIdx.x & 63, wave = threadIdx.x >> 6;
    const int wm = (wave & 1) << 6, wn = (wave >> 1) << 6;
    const int lrow = lane & 15, quad = lane >> 4;
    #pragma unroll
    for (int j = 0; j < 4; j++) {
        int n = n0 + wn + j * 16 + lrow;
        float bv = bias[n];
        #pragma unroll
        for (int i = 0; i < 4; i++) {
            #pragma unroll
            for (int rr = 0; rr < 4; rr++) {
                int m = m0 + wm + i * 16 + quad * 4 + rr;
                out[(size_t)m * C_ + n] = acc[i][j][rr] + bv;
            }
        }
    }
}

// ---------------------------------------------------------------- fused attention (unchanged, passing)
__global__ __launch_bounds__(256, 2) void attn_kernel(const bf16_t* __restrict__ qb,
                                                      const bf16_t* __restrict__ kb,
                                                      const bf16_t* __restrict__ vtb,
                                                      const float* __restrict__ rph,
                                                      const float* __restrict__ rpw,
                                                      bf16_t* __restrict__ aout) {
    const int head = blockIdx.x;
    const int bb = head / NH_, nh = head - bb * NH_;
    const int tid = threadIdx.x;
    const int lane = tid & 63, wave = tid >> 6;
    const int lrow = lane & 15, quad = lane >> 4;

    __shared__ __align__(16) bf16_t qs[32][QSTR];
    __shared__ __align__(16) bf16_t ks[208][QSTR];
    __shared__ __align__(16) bf16_t pb[32][PSTR];
    __shared__ __align__(16) bf16_t rT[64][RSTR];
    __shared__ bf16_t QRh[32][34];
    __shared__ bf16_t QRw[32][34];
    __shared__ float pmax[2][32], psum[2][32];

    bf16x8 z;
    #pragma unroll
    for (int e = 0; e < 8; e++) z[e] = (bf16_t)0.f;

    #pragma unroll
    for (int t2 = 0; t2 < 2; t2++) {
        int u = tid * 2 + t2;
        int which = u >> 8, rem = u & 255;
        int l = rem >> 3, c = (rem & 7) * 8;
        bf16x8 v = z;
        if (l < 27) {
            const float* src = (which ? rpw : rph) + (size_t)l * HD_ + c;
            float4 a = *(const float4*)src;
            float4 b = *(const float4*)(src + 4);
            v[0] = (bf16_t)a.x; v[1] = (bf16_t)a.y; v[2] = (bf16_t)a.z; v[3] = (bf16_t)a.w;
            v[4] = (bf16_t)b.x; v[5] = (bf16_t)b.y; v[6] = (bf16_t)b.z; v[7] = (bf16_t)b.w;
        }
        *(bf16x8*)&rT[which * 32 + l][c] = v;
    }
    for (int v8 = tid; v8 < 208 * 8; v8 += 256) {
        int row = v8 >> 3, col = (v8 & 7) * 8;
        *(bf16x8*)&ks[row][col] =
            (row < HW_) ? *(const bf16x8*)(kb + ((size_t)head * HW_ + row) * HD_ + col) : z;
    }
    for (int u = tid; u < 208 * 5; u += 256) {
        int row = u / 5, c = u - row * 5;
        *(bf16x8*)&ks[row][64 + c * 8] = z;
    }

    bf16x8 vfr[2][7];
    #pragma unroll
    for (int jj = 0; jj < 2; jj++) {
        int hdt = (wave >> 1) * 2 + jj;
        #pragma unroll
        for (int kk = 0; kk < 7; kk++) {
            int col = kk * 32 + quad * 8;
            bool ok = (col < VPAD_);
            bf16x8 t = *(const bf16x8*)(vtb + ((size_t)head * HD_ + hdt * 16 + lrow) * VPAD_
                                        + (ok ? col : 0));
            vfr[jj][kk] = ok ? t : z;
        }
    }

    const int qrow_st = tid >> 3, qcol_st = (tid & 7) * 8;
    bf16x8 qreg = *(const bf16x8*)(qb + ((size_t)head * HW_ + qrow_st) * HD_ + qcol_st);

    __syncthreads();
    if (tid < HW_) {
        int kh = tid / 14, kw = tid - kh * 14;
        ks[tid][64 + kh] = (bf16_t)1.0f;
        ks[tid][78 + kw] = (bf16_t)1.0f;
    }
    if (tid < 96) {
        int row = tid / 3, col = 208 + (tid % 3) * 8;
        *(bf16x8*)&pb[row][col] = z;
    }

    const int wh = wave >> 1, mi = wave & 1;
    const int qit = wave & 1;

    for (int qt = 0; qt < 7; qt++) {
        const int q0 = qt * 32;

        *(bf16x8*)&qs[qrow_st][qcol_st] = qreg;
        __syncthreads();

        #pragma unroll
        for (int t2 = 0; t2 < 2; t2++) {
            int tsk = wave * 2 + t2;
            int which = tsk >> 2, mi2 = (tsk >> 1) & 1, ni = tsk & 1;
            floatx4 a4 = (floatx4){0.f, 0.f, 0.f, 0.f};
            #pragma unroll
            for (int kk = 0; kk < 2; kk++) {
                bf16x8 af  = *(const bf16x8*)&qs[mi2 * 16 + lrow][kk * 32 + quad * 8];
                bf16x8 bf8 = *(const bf16x8*)&rT[which * 32 + ni * 16 + lrow][kk * 32 + quad * 8];
                a4 = __builtin_amdgcn_mfma_f32_16x16x32_bf16(af, bf8, a4, 0, 0, 0);
            }
            int l = ni * 16 + lrow;
            if (l < 27) {
                bf16_t (*QR)[34] = which ? QRw : QRh;
                #pragma unroll
                for (int rr = 0; rr < 4; rr++) QR[mi2 * 16 + quad * 4 + rr][l] = (bf16_t)(a4[rr] * 8.f);
            }
        }
        __syncthreads();

        {
            int row = tid >> 3;
            int kk4 = (tid & 7) * 4;
            int t = q0 + row;
            int h = t / 14, w = t - h * 14;
            bf16x4 pk;
            #pragma unroll
            for (int s = 0; s < 4; s++) {
                int kk = kk4 + s;
                bf16_t val = (bf16_t)0.f;
                if (kk < 14)      val = QRh[row][h - kk + 13];
                else if (kk < 28) val = QRw[row][w - (kk - 14) + 13];
                pk[s] = val;
            }
            *(bf16x4*)&qs[row][64 + kk4] = pk;
        }
        __syncthreads();

        float sv[7][4];
        float m4[4] = {-1e30f, -1e30f, -1e30f, -1e30f};
        #pragma unroll
        for (int t = 0; t < 7; t++) {
            int jt = 2 * t + wh;
            if (jt < 13) {
                floatx4 a4 = (floatx4){0.f, 0.f, 0.f, 0.f};
                #pragma unroll
                for (int kk = 0; kk < 3; kk++) {
                    bf16x8 af  = *(const bf16x8*)&qs[mi * 16 + lrow][kk * 32 + quad * 8];
                    bf16x8 bf8 = *(const bf16x8*)&ks[jt * 16 + lrow][kk * 32 + quad * 8];
                    a4 = __builtin_amdgcn_mfma_f32_16x16x32_bf16(af, bf8, a4, 0, 0, 0);
                }
                int n = jt * 16 + lrow;
                bool valid = (n < HW_);
                #pragma unroll
                for (int rr = 0; rr < 4; rr++) {
                    float s = valid ? a4[rr] : -1e30f;
                    sv[t][rr] = s;
                    m4[rr] = fmaxf(m4[rr], s);
                }
            }
        }
        #pragma unroll
        for (int off = 1; off < 16; off <<= 1)
            #pragma unroll
            for (int rr = 0; rr < 4; rr++) m4[rr] = fmaxf(m4[rr], __shfl_xor(m4[rr], off));
        if (lrow == 0)
            #pragma unroll
            for (int rr = 0; rr < 4; rr++) pmax[wh][mi * 16 + quad * 4 + rr] = m4[rr];
        __syncthreads();

        float mxr[4], s4[4] = {0.f, 0.f, 0.f, 0.f};
        #pragma unroll
        for (int rr = 0; rr < 4; rr++) {
            int qi = mi * 16 + quad * 4 + rr;
            mxr[rr] = fmaxf(pmax[0][qi], pmax[1][qi]);
        }
        #pragma unroll
        for (int t = 0; t < 7; t++) {
            int jt = 2 * t + wh;
            if (jt < 13) {
                int n = jt * 16 + lrow;
                #pragma unroll
                for (int rr = 0; rr < 4; rr++) {
                    float e = __expf(sv[t][rr] - mxr[rr]);
                    s4[rr] += e;
                    pb[mi * 16 + quad * 4 + rr][n] = (bf16_t)e;
                }
            }
        }
        #pragma unroll
        for (int off = 1; off < 16; off <<= 1)
            #pragma unroll
            for (int rr = 0; rr < 4; rr++) s4[rr] += __shfl_xor(s4[rr], off);
        if (lrow == 0)
            #pragma unroll
            for (int rr = 0; rr < 4; rr++) psum[wh][mi * 16 + quad * 4 + rr] = s4[rr];
        __syncthreads();

        const int qrow = qit * 16 + lrow;
        const float inv = 1.f / (psum[0][qrow] + psum[1][qrow]);
        const int t_out = q0 + qrow;

        if (qt < 6) {
            int t = q0 + 32 + qrow_st;
            qreg = (t < HW_) ? *(const bf16x8*)(qb + ((size_t)head * HW_ + t) * HD_ + qcol_st) : z;
        }

        #pragma unroll
        for (int jj = 0; jj < 2; jj++) {
            int hdt = (wave >> 1) * 2 + jj;
            floatx4 a4 = (floatx4){0.f, 0.f, 0.f, 0.f};
            #pragma unroll
            for (int kk = 0; kk < 7; kk++) {
                bf16x8 bf8 = *(const bf16x8*)&pb[qit * 16 + lrow][kk * 32 + quad * 8];
                a4 = __builtin_amdgcn_mfma_f32_16x16x32_bf16(vfr[jj][kk], bf8, a4, 0, 0, 0);
            }
            if (t_out < HW_) {
                int col = nh * HD_ + hdt * 16 + quad * 4;
                ushort4 pk;
                bf16_t hv;
                hv = (bf16_t)(a4[0] * inv); pk.x = __builtin_bit_cast(unsigned short, hv);
                hv = (bf16_t)(a4[1] * inv); pk.y = __builtin_bit_cast(unsigned short, hv);
                hv = (bf16_t)(a4[2] * inv); pk.z = __builtin_bit_cast(unsigned short, hv);
                hv = (bf16_t)(a4[3] * inv); pk.w = __builtin_bit_cast(unsigned short, hv);
                *(ushort4*)(aout + ((size_t)bb * HW_ + t_out) * C_ + col) = pk;
            }
        }
    }
}

// ---------------------------------------------------------------- launcher
extern "C" void kernel_launch(void* const* d_in, const int* in_sizes, int n_in,
                              void* d_out, int out_size, void* d_ws, size_t ws_size,
                              hipStream_t stream) {
    const float* hs    = (const float*)d_in[0];
    const float* wqkv  = (const float*)d_in[1];
    const float* bqkv  = (const float*)d_in[2];
    const float* rph   = (const float*)d_in[3];
    const float* rpw   = (const float*)d_in[4];
    const float* wproj = (const float*)d_in[5];
    const float* bproj = (const float*)d_in[6];
    float* out = (float*)d_out;

    char* ws = (char*)d_ws;
    bf16_t* x_bf   = (bf16_t*)(ws + 0);          // 38,535,168 B; reused as aout
    bf16_t* aout   = x_bf;
    bf16_t* wqkvT  = (bf16_t*)(ws + 38535168);
    bf16_t* wprojT = (bf16_t*)(ws + 42074112);
    bf16_t* qb     = (bf16_t*)(ws + 43253760);
    bf16_t* kb     = (bf16_t*)(ws + 81788928);
    bf16_t* vtb    = (bf16_t*)(ws + 120324096);  // total 161,218,560

    cast_x_kernel<<<9408, 256, 0, stream>>>(hs, x_bf);
    zero_vpad_kernel<<<384, 256, 0, stream>>>(vtb);
    transpose_cast_kernel<<<dim3(72, 24), dim3(32, 8), 0, stream>>>(wqkv, wqkvT, 768, 2304);
    transpose_cast_kernel<<<dim3(24, 24), dim3(32, 8), 0, stream>>>(wproj, wprojT, 768, 768);
    qkv_gemm_kernel<<<98 * 9, 512, 0, stream>>>(x_bf, wqkvT, bqkv, qb, kb, vtb);
    attn_kernel<<<B_ * NH_, 256, 0, stream>>>(qb, kb, vtb, rph, rpw, aout);
    proj_gemm_kernel<<<1176, 256, 0, stream>>>(aout, wprojT, bproj, out);
}

// Round 10
// 390.272 us; speedup vs baseline: 1.0356x; 1.0356x over previous
//
#include <hip/hip_runtime.h>

typedef __bf16 bf16_t;
typedef __bf16 bf16x4 __attribute__((ext_vector_type(4)));
typedef __bf16 bf16x8 __attribute__((ext_vector_type(8)));
typedef float floatx4 __attribute__((ext_vector_type(4)));

#define B_    128
#define H_    14
#define HW_   196
#define C_    768
#define NH_   12
#define HD_   64
#define M_    25088
#define NQKV_ 2304
#define KDIM_ 768
#define BK_   64    // GEMM K-tile
#define NKT_  12    // KDIM_/BK_
#define VPAD_ 208   // v^T global row length (16B-aligned)
#define RSTR  72    // rT staging stride (bf16)
#define QSTR  104   // q'/k' augmented row stride in bf16
#define PSTR  232   // pb LDS row stride in bf16

#define CASTBLKS 9408            // cast blocks: 25088*768/(256*8)
#define TR1X 72                  // wqkv col-tiles (2304/32)
#define TRX  96                  // + wproj col-tiles (768/32)
#define TRY  24                  // row-tiles (768/32)

// ---------------------------------------------------------------- async 16B global->LDS
__device__ __forceinline__ void async_cp16(const void* g, void* l) {
    __builtin_amdgcn_global_load_lds((const __attribute__((address_space(1))) void*)g,
                                     (__attribute__((address_space(3))) void*)l, 16, 0, 0);
}

// ---------------------------------------------------------------- fused prep:
// blocks [0, CASTBLKS)            : cast hidden_states fp32 -> bf16 (x_bf)
// blocks [CASTBLKS, +TRX*TRY)     : transpose+cast wqkv / wproj
// (disjoint outputs; no intra-kernel ordering needed)
__global__ __launch_bounds__(256) void prep_kernel(const float* __restrict__ hs,
                                                   bf16_t* __restrict__ x_bf,
                                                   const float* __restrict__ wqkv,
                                                   bf16_t* __restrict__ wqkvT,
                                                   const float* __restrict__ wproj,
                                                   bf16_t* __restrict__ wprojT) {
    __shared__ float tile[32][33];
    const int bid = blockIdx.x, tid = threadIdx.x;

    if (bid < CASTBLKS) {
        size_t i = ((size_t)bid * 256 + tid) * 8;
        float4 a = *(const float4*)(hs + i);
        float4 b = *(const float4*)(hs + i + 4);
        bf16x8 v;
        v[0] = (bf16_t)a.x; v[1] = (bf16_t)a.y; v[2] = (bf16_t)a.z; v[3] = (bf16_t)a.w;
        v[4] = (bf16_t)b.x; v[5] = (bf16_t)b.y; v[6] = (bf16_t)b.z; v[7] = (bf16_t)b.w;
        *(bf16x8*)(x_bf + i) = v;
        return;
    }

    const int tb  = bid - CASTBLKS;
    const int bx0 = tb % TRX, by = tb / TRX;          // by in [0,24)
    const bool is1 = (bx0 < TR1X);
    const int bx  = is1 ? bx0 : bx0 - TR1X;
    const float* in  = is1 ? wqkv  : wproj;
    bf16_t*      out = is1 ? wqkvT : wprojT;
    const int rows = 768, cols = is1 ? NQKV_ : C_;

    const int tx = tid & 31, ty = tid >> 5;           // 32 x 8
    const int c0 = bx * 32, r0 = by * 32;
    for (int i = ty; i < 32; i += 8) {
        int r = r0 + i, c = c0 + tx;
        if (r < rows && c < cols) tile[i][tx] = in[(size_t)r * cols + c];
    }
    __syncthreads();
    for (int i = ty; i < 32; i += 8) {
        int orow = c0 + i;            // output row = input col
        int oc   = r0 + tx;           // output col = input row
        if (orow < cols && oc < rows)
            out[(size_t)orow * rows + oc] = (bf16_t)tile[tx][i];
    }
}

// ---------------------------------------------------------------- staging: one 128x64 tile slice (256 thr)
__device__ __forceinline__ void stage128(const bf16_t* __restrict__ G, int g0, int kt,
                                         bf16_t (*Lb)[BK_], int tid) {
    const int sr = tid >> 3, cc = tid & 7;
    #pragma unroll
    for (int i = 0; i < 4; i++) {
        int row  = sr + i * 32;                 // in-tile row 0..127
        int scol = ((cc ^ (row & 7)) * 8);      // swizzled source k-chunk
        async_cp16(G + (size_t)(g0 + row) * KDIM_ + kt * BK_ + scol, &Lb[row][cc * 8]);
    }
}

// ---------------------------------------------------------------- staging: one 256x64 tile (512 thr)
__device__ __forceinline__ void stage256(const bf16_t* __restrict__ G, int g0, int kt,
                                         bf16_t (*Lb)[BK_], int tid) {
    #pragma unroll
    for (int r = 0; r < 4; r++) {
        int idx = r * 512 + tid;                // 0..2047
        int row = idx >> 3, cc = idx & 7;
        int scol = (cc ^ (row & 7)) * 8;        // source-side XOR swizzle
        async_cp16(G + (size_t)(g0 + row) * KDIM_ + kt * BK_ + scol, &Lb[row][cc * 8]);
    }
}

// ---------------------------------------------------------------- 128-tile GEMM core, double-buffered.
__device__ __forceinline__ void gemm128_pipe(const bf16_t* __restrict__ A,
                                             const bf16_t* __restrict__ Bt,
                                             int m0, int n0,
                                             floatx4 acc[4][4],
                                             bf16_t (*As)[BK_], bf16_t (*Bs)[BK_]) {
    const int tid  = threadIdx.x;
    const int lane = tid & 63, wave = tid >> 6;
    const int wm = (wave & 1) << 6, wn = (wave >> 1) << 6;
    const int lrow = lane & 15, quad = lane >> 4;

    #pragma unroll
    for (int i = 0; i < 4; i++)
        #pragma unroll
        for (int j = 0; j < 4; j++) acc[i][j] = (floatx4){0.f, 0.f, 0.f, 0.f};

    stage128(A,  m0, 0, As, tid);
    stage128(Bt, n0, 0, Bs, tid);

    for (int kt = 0; kt < NKT_; kt++) {
        __builtin_amdgcn_sched_barrier(0);
        asm volatile("s_waitcnt vmcnt(0) lgkmcnt(0)" ::: "memory");
        __builtin_amdgcn_s_barrier();
        __builtin_amdgcn_sched_barrier(0);

        bf16_t (*Ab)[BK_] = As + (kt & 1) * 128;
        bf16_t (*Bb)[BK_] = Bs + (kt & 1) * 128;

        if (kt + 1 < NKT_) {
            stage128(A,  m0, kt + 1, As + ((kt + 1) & 1) * 128, tid);
            stage128(Bt, n0, kt + 1, Bs + ((kt + 1) & 1) * 128, tid);
        }

        #pragma unroll
        for (int kh = 0; kh < 2; kh++) {
            bf16x8 af[4], bfr[4];
            #pragma unroll
            for (int i = 0; i < 4; i++) {
                int rw = wm + i * 16 + lrow;
                af[i] = *(const bf16x8*)&Ab[rw][((kh * 4 + quad) ^ (rw & 7)) * 8];
            }
            #pragma unroll
            for (int j = 0; j < 4; j++) {
                int rw = wn + j * 16 + lrow;
                bfr[j] = *(const bf16x8*)&Bb[rw][((kh * 4 + quad) ^ (rw & 7)) * 8];
            }
            #pragma unroll
            for (int i = 0; i < 4; i++)
                #pragma unroll
                for (int j = 0; j < 4; j++)
                    acc[i][j] = __builtin_amdgcn_mfma_f32_16x16x32_bf16(af[i], bfr[j], acc[i][j], 0, 0, 0);
        }
    }
    __syncthreads();
}

// ---------------------------------------------------------------- QKV GEMM: 256x256 tile, 8 waves,
// double-buffered LDS (128 KB), 4 phases/K-tile, XCD-bijective block swizzle (R7 schedule:
// stage next-A at ph0, next-B at ph1, vmcnt(0) at ph3 on 2-3-phase-old loads).
// q written pre-scaled by 0.125.
__global__ __launch_bounds__(512, 2) void qkv_gemm_kernel(const bf16_t* __restrict__ A,
                                                          const bf16_t* __restrict__ Bt,
                                                          const float* __restrict__ bias,
                                                          bf16_t* __restrict__ qb,
                                                          bf16_t* __restrict__ kb,
                                                          bf16_t* __restrict__ vtb) {
    __shared__ __align__(16) char smem[131072];            // Ab[2][256][64] | Bb[2][256][64]
    bf16_t (*AbAll)[256][64] = (bf16_t(*)[256][64])smem;
    bf16_t (*BbAll)[256][64] = (bf16_t(*)[256][64])(smem + 65536);
    bf16_t (*Cs)[136]        = (bf16_t(*)[136])smem;       // epilogue union: 256x128 half (69,632 B)

    const int tid  = threadIdx.x;
    const int lane = tid & 63, wave = tid >> 6;
    const int wr = wave >> 2, wc = wave & 3;               // 2M x 4N wave grid
    const int lrow = lane & 15, quad = lane >> 4;
    const int c0 = ((quad ^ (lrow & 7)) * 8);              // kh=0 swizzled chunk
    const int c1 = (((4 + quad) ^ (lrow & 7)) * 8);        // kh=1

    // XCD-bijective swizzle (m204): nwg=882 -> q=110, r=2.
    const int nwg = 98 * 9;
    const int qq = nwg >> 3, rr8 = nwg & 7;
    const int xcd = blockIdx.x & 7, lid = blockIdx.x >> 3;
    const int wgid = (xcd < rr8 ? xcd * (qq + 1) : rr8 * (qq + 1) + (xcd - rr8) * qq) + lid;
    const int bm = wgid / 9, bn = wgid % 9;
    const int m0 = bm * 256, n0 = bn * 256;

    floatx4 acc[8][4];
    #pragma unroll
    for (int i = 0; i < 8; i++)
        #pragma unroll
        for (int j = 0; j < 4; j++) acc[i][j] = (floatx4){0.f, 0.f, 0.f, 0.f};

    // prologue: stage K-tile 0 into buffer 0
    stage256(A,  m0, 0, AbAll[0], tid);
    stage256(Bt, n0, 0, BbAll[0], tid);
    asm volatile("s_waitcnt vmcnt(0)" ::: "memory");
    __builtin_amdgcn_s_barrier();
    __builtin_amdgcn_sched_barrier(0);

    for (int kt = 0; kt < NKT_; kt++) {
        bf16_t (*Ab)[64] = AbAll[kt & 1];
        bf16_t (*Bb)[64] = BbAll[kt & 1];
        const int arow = wr * 128 + lrow;
        const int brow = wc * 64 + lrow;

        bf16x8 af[4][2], bfA[2][2], bfB[2][2];

        // ---- phase 0: ds_read af(m-half 0) + bfA(n-q 0); stage next A-tile
        #pragma unroll
        for (int i = 0; i < 4; i++) {
            af[i][0] = *(const bf16x8*)&Ab[arow + i * 16][c0];
            af[i][1] = *(const bf16x8*)&Ab[arow + i * 16][c1];
        }
        #pragma unroll
        for (int j = 0; j < 2; j++) {
            bfA[j][0] = *(const bf16x8*)&Bb[brow + j * 16][c0];
            bfA[j][1] = *(const bf16x8*)&Bb[brow + j * 16][c1];
        }
        if (kt < NKT_ - 1) stage256(A, m0, kt + 1, AbAll[(kt + 1) & 1], tid);
        __builtin_amdgcn_s_barrier();
        asm volatile("s_waitcnt lgkmcnt(0)" ::: "memory");
        __builtin_amdgcn_sched_barrier(0);
        __builtin_amdgcn_s_setprio(1);
        #pragma unroll
        for (int i = 0; i < 4; i++)
            #pragma unroll
            for (int j = 0; j < 2; j++) {
                acc[i][j] = __builtin_amdgcn_mfma_f32_16x16x32_bf16(af[i][0], bfA[j][0], acc[i][j], 0, 0, 0);
                acc[i][j] = __builtin_amdgcn_mfma_f32_16x16x32_bf16(af[i][1], bfA[j][1], acc[i][j], 0, 0, 0);
            }
        __builtin_amdgcn_s_setprio(0);
        __builtin_amdgcn_sched_barrier(0);
        __builtin_amdgcn_s_barrier();

        // ---- phase 1: ds_read bfB(n-q 1); stage next B-tile
        #pragma unroll
        for (int j = 0; j < 2; j++) {
            bfB[j][0] = *(const bf16x8*)&Bb[brow + 32 + j * 16][c0];
            bfB[j][1] = *(const bf16x8*)&Bb[brow + 32 + j * 16][c1];
        }
        if (kt < NKT_ - 1) stage256(Bt, n0, kt + 1, BbAll[(kt + 1) & 1], tid);
        __builtin_amdgcn_s_barrier();
        asm volatile("s_waitcnt lgkmcnt(0)" ::: "memory");
        __builtin_amdgcn_sched_barrier(0);
        __builtin_amdgcn_s_setprio(1);
        #pragma unroll
        for (int i = 0; i < 4; i++)
            #pragma unroll
            for (int j = 0; j < 2; j++) {
                acc[i][2 + j] = __builtin_amdgcn_mfma_f32_16x16x32_bf16(af[i][0], bfB[j][0], acc[i][2 + j], 0, 0, 0);
                acc[i][2 + j] = __builtin_amdgcn_mfma_f32_16x16x32_bf16(af[i][1], bfB[j][1], acc[i][2 + j], 0, 0, 0);
            }
        __builtin_amdgcn_s_setprio(0);
        __builtin_amdgcn_sched_barrier(0);
        __builtin_amdgcn_s_barrier();

        // ---- phase 2: ds_read af(m-half 1)
        #pragma unroll
        for (int i = 0; i < 4; i++) {
            af[i][0] = *(const bf16x8*)&Ab[arow + 64 + i * 16][c0];
            af[i][1] = *(const bf16x8*)&Ab[arow + 64 + i * 16][c1];
        }
        __builtin_amdgcn_s_barrier();
        asm volatile("s_waitcnt lgkmcnt(0)" ::: "memory");
        __builtin_amdgcn_sched_barrier(0);
        __builtin_amdgcn_s_setprio(1);
        #pragma unroll
        for (int i = 0; i < 4; i++)
            #pragma unroll
            for (int j = 0; j < 2; j++) {
                acc[4 + i][j] = __builtin_amdgcn_mfma_f32_16x16x32_bf16(af[i][0], bfA[j][0], acc[4 + i][j], 0, 0, 0);
                acc[4 + i][j] = __builtin_amdgcn_mfma_f32_16x16x32_bf16(af[i][1], bfA[j][1], acc[4 + i][j], 0, 0, 0);
            }
        __builtin_amdgcn_s_setprio(0);
        __builtin_amdgcn_sched_barrier(0);
        __builtin_amdgcn_s_barrier();

        // ---- phase 3: MFMA only; then drain next-tile stages (issued 2-3 phases ago)
        __builtin_amdgcn_s_setprio(1);
        #pragma unroll
        for (int i = 0; i < 4; i++)
            #pragma unroll
            for (int j = 0; j < 2; j++) {
                acc[4 + i][2 + j] = __builtin_amdgcn_mfma_f32_16x16x32_bf16(af[i][0], bfB[j][0], acc[4 + i][2 + j], 0, 0, 0);
                acc[4 + i][2 + j] = __builtin_amdgcn_mfma_f32_16x16x32_bf16(af[i][1], bfB[j][1], acc[4 + i][2 + j], 0, 0, 0);
            }
        __builtin_amdgcn_s_setprio(0);
        __builtin_amdgcn_sched_barrier(0);
        asm volatile("s_waitcnt vmcnt(0)" ::: "memory");
        __builtin_amdgcn_s_barrier();
        __builtin_amdgcn_sched_barrier(0);
    }

    // ---------------- epilogue
    const int sel = n0 / C_;                    // 0=q 1=k 2=v (256-tiles never straddle)

    if (sel == 2) {
        #pragma unroll
        for (int j = 0; j < 4; j++) {
            int n = n0 + wc * 64 + j * 16 + lrow;
            float bv = bias[n];
            int nc = n - 2 * C_;
            int nh = nc >> 6, hd = nc & 63;
            #pragma unroll
            for (int i = 0; i < 8; i++) {
                int m = m0 + wr * 128 + i * 16 + quad * 4;
                int b = m / HW_, t = m - b * HW_;
                int head = b * NH_ + nh;
                ushort4 pk;
                bf16_t h;
                h = (bf16_t)(acc[i][j][0] + bv); pk.x = __builtin_bit_cast(unsigned short, h);
                h = (bf16_t)(acc[i][j][1] + bv); pk.y = __builtin_bit_cast(unsigned short, h);
                h = (bf16_t)(acc[i][j][2] + bv); pk.z = __builtin_bit_cast(unsigned short, h);
                h = (bf16_t)(acc[i][j][3] + bv); pk.w = __builtin_bit_cast(unsigned short, h);
                *(ushort4*)(vtb + ((size_t)head * HD_ + hd) * VPAD_ + t) = pk;
            }
        }
    } else {
        const float sc = (sel == 0) ? 0.125f : 1.0f;
        bf16_t* dst = sel ? kb : qb;
        const int n0s = n0 - sel * C_;
        // two half-passes through Cs[256][136]
        #pragma unroll
        for (int hh = 0; hh < 2; hh++) {
            __syncthreads();                     // K-loop LDS / previous half copy done
            if ((wc >> 1) == hh) {
                #pragma unroll
                for (int j = 0; j < 4; j++) {
                    int n = n0 + wc * 64 + j * 16 + lrow;
                    float bv = bias[n];
                    int ccol = (wc & 1) * 64 + j * 16 + lrow;   // col within half: 0..127
                    #pragma unroll
                    for (int i = 0; i < 8; i++)
                        #pragma unroll
                        for (int rr = 0; rr < 4; rr++)
                            Cs[wr * 128 + i * 16 + quad * 4 + rr][ccol] =
                                (bf16_t)((acc[i][j][rr] + bv) * sc);
                }
            }
            __syncthreads();
            // copy 256 x 128 half: 4096 uint4, 8 per thread
            #pragma unroll
            for (int u = 0; u < 8; u++) {
                int idx = tid + u * 512;
                int rr = idx >> 4, c = idx & 15;
                int m = m0 + rr;
                int b = m / HW_, t = m - b * HW_;
                int ncol = n0s + hh * 128 + c * 8;
                int nh = ncol >> 6, hd = ncol & 63;
                *(uint4*)(dst + (((size_t)(b * NH_ + nh)) * HW_ + t) * HD_ + hd) =
                    *(const uint4*)&Cs[rr][c * 8];
            }
        }
    }
}

// ---------------------------------------------------------------- proj GEMM + bias -> fp32 out
__global__ __launch_bounds__(256) void proj_gemm_kernel(const bf16_t* __restrict__ A,
                                                        const bf16_t* __restrict__ Bt,
                                                        const float* __restrict__ bias,
                                                        float* __restrict__ out) {
    __shared__ __align__(16) bf16_t As[256][BK_];   // double-buffered
    __shared__ __align__(16) bf16_t Bs[256][BK_];
    const int lin = blockIdx.x;
    const int g = lin / 24, r = lin - g * 24;
    const int m0 = (g * 4 + (r & 3)) * 128;
    const int n0 = (r >> 2) * 128;
    floatx4 acc[4][4];
    gemm128_pipe(A, Bt, m0, n0, acc, As, Bs);

    const int lane = threadIdx.x & 63, wave = threadIdx.x >> 6;
    const int wm = (wave & 1) << 6, wn = (wave >> 1) << 6;
    const int lrow = lane & 15, quad = lane >> 4;
    #pragma unroll
    for (int j = 0; j < 4; j++) {
        int n = n0 + wn + j * 16 + lrow;
        float bv = bias[n];
        #pragma unroll
        for (int i = 0; i < 4; i++) {
            #pragma unroll
            for (int rr = 0; rr < 4; rr++) {
                int m = m0 + wm + i * 16 + quad * 4 + rr;
                out[(size_t)m * C_ + n] = acc[i][j][rr] + bv;
            }
        }
    }
}

// ---------------------------------------------------------------- fused attention
// One block per head; k'/rel tables staged once; v^T in registers (pad cols >=196 masked
// at load -> no zero_vpad kernel needed); 7 q-tile rounds.
__global__ __launch_bounds__(256, 2) void attn_kernel(const bf16_t* __restrict__ qb,
                                                      const bf16_t* __restrict__ kb,
                                                      const bf16_t* __restrict__ vtb,
                                                      const float* __restrict__ rph,
                                                      const float* __restrict__ rpw,
                                                      bf16_t* __restrict__ aout) {
    const int head = blockIdx.x;
    const int bb = head / NH_, nh = head - bb * NH_;
    const int tid = threadIdx.x;
    const int lane = tid & 63, wave = tid >> 6;
    const int lrow = lane & 15, quad = lane >> 4;

    __shared__ __align__(16) bf16_t qs[32][QSTR];
    __shared__ __align__(16) bf16_t ks[208][QSTR];
    __shared__ __align__(16) bf16_t pb[32][PSTR];
    __shared__ __align__(16) bf16_t rT[64][RSTR];
    __shared__ bf16_t QRh[32][34];
    __shared__ bf16_t QRw[32][34];
    __shared__ float pmax[2][32], psum[2][32];

    bf16x8 z;
    #pragma unroll
    for (int e = 0; e < 8; e++) z[e] = (bf16_t)0.f;

    #pragma unroll
    for (int t2 = 0; t2 < 2; t2++) {
        int u = tid * 2 + t2;
        int which = u >> 8, rem = u & 255;
        int l = rem >> 3, c = (rem & 7) * 8;
        bf16x8 v = z;
        if (l < 27) {
            const float* src = (which ? rpw : rph) + (size_t)l * HD_ + c;
            float4 a = *(const float4*)src;
            float4 b = *(const float4*)(src + 4);
            v[0] = (bf16_t)a.x; v[1] = (bf16_t)a.y; v[2] = (bf16_t)a.z; v[3] = (bf16_t)a.w;
            v[4] = (bf16_t)b.x; v[5] = (bf16_t)b.y; v[6] = (bf16_t)b.z; v[7] = (bf16_t)b.w;
        }
        *(bf16x8*)&rT[which * 32 + l][c] = v;
    }
    for (int v8 = tid; v8 < 208 * 8; v8 += 256) {
        int row = v8 >> 3, col = (v8 & 7) * 8;
        *(bf16x8*)&ks[row][col] =
            (row < HW_) ? *(const bf16x8*)(kb + ((size_t)head * HW_ + row) * HD_ + col) : z;
    }
    for (int u = tid; u < 208 * 5; u += 256) {
        int row = u / 5, c = u - row * 5;
        *(bf16x8*)&ks[row][64 + c * 8] = z;
    }

    // v^T fragments into registers; pad columns (>=196) masked to zero at load
    bf16x8 vfr[2][7];
    #pragma unroll
    for (int jj = 0; jj < 2; jj++) {
        int hdt = (wave >> 1) * 2 + jj;
        #pragma unroll
        for (int kk = 0; kk < 7; kk++) {
            int col = kk * 32 + quad * 8;
            bf16x8 t = z;
            if (col < HW_) {
                t = *(const bf16x8*)(vtb + ((size_t)head * HD_ + hdt * 16 + lrow) * VPAD_ + col);
                #pragma unroll
                for (int e = 0; e < 8; e++)
                    if (col + e >= HW_) t[e] = (bf16_t)0.f;
            }
            vfr[jj][kk] = t;
        }
    }

    const int qrow_st = tid >> 3, qcol_st = (tid & 7) * 8;
    bf16x8 qreg = *(const bf16x8*)(qb + ((size_t)head * HW_ + qrow_st) * HD_ + qcol_st);

    __syncthreads();
    if (tid < HW_) {
        int kh = tid / 14, kw = tid - kh * 14;
        ks[tid][64 + kh] = (bf16_t)1.0f;
        ks[tid][78 + kw] = (bf16_t)1.0f;
    }
    if (tid < 96) {
        int row = tid / 3, col = 208 + (tid % 3) * 8;
        *(bf16x8*)&pb[row][col] = z;
    }

    const int wh = wave >> 1, mi = wave & 1;
    const int qit = wave & 1;

    for (int qt = 0; qt < 7; qt++) {
        const int q0 = qt * 32;

        *(bf16x8*)&qs[qrow_st][qcol_st] = qreg;
        __syncthreads();

        #pragma unroll
        for (int t2 = 0; t2 < 2; t2++) {
            int tsk = wave * 2 + t2;
            int which = tsk >> 2, mi2 = (tsk >> 1) & 1, ni = tsk & 1;
            floatx4 a4 = (floatx4){0.f, 0.f, 0.f, 0.f};
            #pragma unroll
            for (int kk = 0; kk < 2; kk++) {
                bf16x8 af  = *(const bf16x8*)&qs[mi2 * 16 + lrow][kk * 32 + quad * 8];
                bf16x8 bf8 = *(const bf16x8*)&rT[which * 32 + ni * 16 + lrow][kk * 32 + quad * 8];
                a4 = __builtin_amdgcn_mfma_f32_16x16x32_bf16(af, bf8, a4, 0, 0, 0);
            }
            int l = ni * 16 + lrow;
            if (l < 27) {
                bf16_t (*QR)[34] = which ? QRw : QRh;
                #pragma unroll
                for (int rr = 0; rr < 4; rr++) QR[mi2 * 16 + quad * 4 + rr][l] = (bf16_t)(a4[rr] * 8.f);
            }
        }
        __syncthreads();

        {
            int row = tid >> 3;
            int kk4 = (tid & 7) * 4;
            int t = q0 + row;
            int h = t / 14, w = t - h * 14;
            bf16x4 pk;
            #pragma unroll
            for (int s = 0; s < 4; s++) {
                int kk = kk4 + s;
                bf16_t val = (bf16_t)0.f;
                if (kk < 14)      val = QRh[row][h - kk + 13];
                else if (kk < 28) val = QRw[row][w - (kk - 14) + 13];
                pk[s] = val;
            }
            *(bf16x4*)&qs[row][64 + kk4] = pk;
        }
        __syncthreads();

        float sv[7][4];
        float m4[4] = {-1e30f, -1e30f, -1e30f, -1e30f};
        #pragma unroll
        for (int t = 0; t < 7; t++) {
            int jt = 2 * t + wh;
            if (jt < 13) {
                floatx4 a4 = (floatx4){0.f, 0.f, 0.f, 0.f};
                #pragma unroll
                for (int kk = 0; kk < 3; kk++) {
                    bf16x8 af  = *(const bf16x8*)&qs[mi * 16 + lrow][kk * 32 + quad * 8];
                    bf16x8 bf8 = *(const bf16x8*)&ks[jt * 16 + lrow][kk * 32 + quad * 8];
                    a4 = __builtin_amdgcn_mfma_f32_16x16x32_bf16(af, bf8, a4, 0, 0, 0);
                }
                int n = jt * 16 + lrow;
                bool valid = (n < HW_);
                #pragma unroll
                for (int rr = 0; rr < 4; rr++) {
                    float s = valid ? a4[rr] : -1e30f;
                    sv[t][rr] = s;
                    m4[rr] = fmaxf(m4[rr], s);
                }
            }
        }
        #pragma unroll
        for (int off = 1; off < 16; off <<= 1)
            #pragma unroll
            for (int rr = 0; rr < 4; rr++) m4[rr] = fmaxf(m4[rr], __shfl_xor(m4[rr], off));
        if (lrow == 0)
            #pragma unroll
            for (int rr = 0; rr < 4; rr++) pmax[wh][mi * 16 + quad * 4 + rr] = m4[rr];
        __syncthreads();

        float mxr[4], s4[4] = {0.f, 0.f, 0.f, 0.f};
        #pragma unroll
        for (int rr = 0; rr < 4; rr++) {
            int qi = mi * 16 + quad * 4 + rr;
            mxr[rr] = fmaxf(pmax[0][qi], pmax[1][qi]);
        }
        #pragma unroll
        for (int t = 0; t < 7; t++) {
            int jt = 2 * t + wh;
            if (jt < 13) {
                int n = jt * 16 + lrow;
                #pragma unroll
                for (int rr = 0; rr < 4; rr++) {
                    float e = __expf(sv[t][rr] - mxr[rr]);
                    s4[rr] += e;
                    pb[mi * 16 + quad * 4 + rr][n] = (bf16_t)e;
                }
            }
        }
        #pragma unroll
        for (int off = 1; off < 16; off <<= 1)
            #pragma unroll
            for (int rr = 0; rr < 4; rr++) s4[rr] += __shfl_xor(s4[rr], off);
        if (lrow == 0)
            #pragma unroll
            for (int rr = 0; rr < 4; rr++) psum[wh][mi * 16 + quad * 4 + rr] = s4[rr];
        __syncthreads();

        const int qrow = qit * 16 + lrow;
        const float inv = 1.f / (psum[0][qrow] + psum[1][qrow]);
        const int t_out = q0 + qrow;

        if (qt < 6) {
            int t = q0 + 32 + qrow_st;
            qreg = (t < HW_) ? *(const bf16x8*)(qb + ((size_t)head * HW_ + t) * HD_ + qcol_st) : z;
        }

        #pragma unroll
        for (int jj = 0; jj < 2; jj++) {
            int hdt = (wave >> 1) * 2 + jj;
            floatx4 a4 = (floatx4){0.f, 0.f, 0.f, 0.f};
            #pragma unroll
            for (int kk = 0; kk < 7; kk++) {
                bf16x8 bf8 = *(const bf16x8*)&pb[qit * 16 + lrow][kk * 32 + quad * 8];
                a4 = __builtin_amdgcn_mfma_f32_16x16x32_bf16(vfr[jj][kk], bf8, a4, 0, 0, 0);
            }
            if (t_out < HW_) {
                int col = nh * HD_ + hdt * 16 + quad * 4;
                ushort4 pk;
                bf16_t hv;
                hv = (bf16_t)(a4[0] * inv); pk.x = __builtin_bit_cast(unsigned short, hv);
                hv = (bf16_t)(a4[1] * inv); pk.y = __builtin_bit_cast(unsigned short, hv);
                hv = (bf16_t)(a4[2] * inv); pk.z = __builtin_bit_cast(unsigned short, hv);
                hv = (bf16_t)(a4[3] * inv); pk.w = __builtin_bit_cast(unsigned short, hv);
                *(ushort4*)(aout + ((size_t)bb * HW_ + t_out) * C_ + col) = pk;
            }
        }
    }
}

// ---------------------------------------------------------------- launcher (4 launches)
extern "C" void kernel_launch(void* const* d_in, const int* in_sizes, int n_in,
                              void* d_out, int out_size, void* d_ws, size_t ws_size,
                              hipStream_t stream) {
    const float* hs    = (const float*)d_in[0];
    const float* wqkv  = (const float*)d_in[1];
    const float* bqkv  = (const float*)d_in[2];
    const float* rph   = (const float*)d_in[3];
    const float* rpw   = (const float*)d_in[4];
    const float* wproj = (const float*)d_in[5];
    const float* bproj = (const float*)d_in[6];
    float* out = (float*)d_out;

    char* ws = (char*)d_ws;
    bf16_t* x_bf   = (bf16_t*)(ws + 0);          // 38,535,168 B; reused as aout
    bf16_t* aout   = x_bf;
    bf16_t* wqkvT  = (bf16_t*)(ws + 38535168);
    bf16_t* wprojT = (bf16_t*)(ws + 42074112);
    bf16_t* qb     = (bf16_t*)(ws + 43253760);
    bf16_t* kb     = (bf16_t*)(ws + 81788928);
    bf16_t* vtb    = (bf16_t*)(ws + 120324096);  // total 161,218,560

    prep_kernel<<<CASTBLKS + TRX * TRY, 256, 0, stream>>>(hs, x_bf, wqkv, wqkvT, wproj, wprojT);
    qkv_gemm_kernel<<<98 * 9, 512, 0, stream>>>(x_bf, wqkvT, bqkv, qb, kb, vtb);
    attn_kernel<<<B_ * NH_, 256, 0, stream>>>(qb, kb, vtb, rph, rpw, aout);
    proj_gemm_kernel<<<1176, 256, 0, stream>>>(aout, wprojT, bproj, out);
}